// Round 16
// baseline (224.801 us; speedup 1.0000x reference)
//
#include <hip/hip_runtime.h>
#include <stdint.h>

// Self-attention, B=8 S=2048 D=E=512, fp32 in/out, bf16 MFMA internally.
//   xconv/wconv: unchanged (R11/R15).
//   qkv v6: MERGED Q+K blocks (one A-tile feeds both B-tiles): BK=32, 16 iters,
//     48 KB LDS (A/Bq/Bk double-buffered), accQ+accK in AGPRs, two sequential
//     LDS-transposed epilogues. V blocks keep the R11 BK=64 path verbatim.
//     Grid 1536 -> 1024 blocks (2 occupancy rounds instead of 3); A staging
//     and A global traffic halve for Q/K. XCD pinning preserved (gid&7).
//   attn v9: unchanged (98.2-100.5 µs control across 5 rounds).

using f32x4 = __attribute__((ext_vector_type(4))) float;
using s16x8 = __attribute__((ext_vector_type(8))) short;
using u16x4 = __attribute__((ext_vector_type(4))) unsigned short;

#define S_LEN 2048
#define EMB   512

#define ASYNC16(g, l)                                                     \
  __builtin_amdgcn_global_load_lds(                                       \
      (const __attribute__((address_space(1))) void*)(g),                 \
      (__attribute__((address_space(3))) void*)(l), 16, 0, 0)

__device__ __forceinline__ unsigned short f2bf(float f) {
  union { float f; unsigned u; } v; v.f = f;
  unsigned r = v.u + 0x7fffu + ((v.u >> 16) & 1u);   // RNE
  return (unsigned short)(r >> 16);
}

// ---------------- kernel 0: x fp32 -> bf16 ----------------
__global__ __launch_bounds__(256) void xconv_kernel(
    const float* __restrict__ x, short* __restrict__ xb) {
  int i = (blockIdx.x * 256 + threadIdx.x) * 8;
  f32x4 a = *(const f32x4*)(x + i);
  f32x4 b = *(const f32x4*)(x + i + 4);
  s16x8 h;
  h[0] = (short)f2bf(a[0]); h[1] = (short)f2bf(a[1]);
  h[2] = (short)f2bf(a[2]); h[3] = (short)f2bf(a[3]);
  h[4] = (short)f2bf(b[0]); h[5] = (short)f2bf(b[1]);
  h[6] = (short)f2bf(b[2]); h[7] = (short)f2bf(b[3]);
  *(s16x8*)(xb + i) = h;
}

// ---------------- kernel 1: weight transpose (LDS-tiled, coalesced) ----------------
__global__ __launch_bounds__(256) void wconv_kernel(
    const float* __restrict__ Wq, const float* __restrict__ Wk,
    const float* __restrict__ Wv, short* __restrict__ Wt) {
  __shared__ float T[64][65];
  int bid = blockIdx.x;
  int mat = bid >> 6;
  int t   = bid & 63;
  int k0  = (t & 7) << 6, n0 = (t >> 3) << 6;
  const float* W = (mat == 0) ? Wq : (mat == 1) ? Wk : Wv;
  int tid = threadIdx.x;
  int rr = tid >> 4, cc = tid & 15;
#pragma unroll
  for (int p = 0; p < 4; ++p) {
    int row = p * 16 + rr;
    f32x4 v = *(const f32x4*)(W + (size_t)(k0 + row) * 512 + n0 + cc * 4);
#pragma unroll
    for (int j = 0; j < 4; ++j) T[row][cc * 4 + j] = v[j];
  }
  __syncthreads();
  short* D = Wt + (size_t)mat * 262144;
#pragma unroll
  for (int p = 0; p < 4; ++p) {
    int nrow = p * 16 + rr;
    u16x4 h;
#pragma unroll
    for (int j = 0; j < 4; ++j) h[j] = f2bf(T[cc * 4 + j][nrow]);
    *(u16x4*)(D + (size_t)(n0 + nrow) * 512 + k0 + cc * 4) = h;
  }
}

// ---------------- kernel 2: QKV GEMM v6 (merged Q+K blocks; V = R11 path) ----------------
// grid 1024: xcd = gid&7; s = gid>>3 in [0,128).
//   s <  64: merged Q+K block, BK=32: mt_l=s>>2, nt=s&3.
//   s >= 64: V block (R11 BK=64), s2=s-64: mt_l=s2>>2, nt=s2&3.
__global__ __launch_bounds__(256) void qkv_gemm(
    const short* __restrict__ xb, const short* __restrict__ Wt,
    const float* __restrict__ bq, const float* __restrict__ bk,
    const float* __restrict__ bv,
    short* __restrict__ Qg, short* __restrict__ Kg, short* __restrict__ VTg) {
  __shared__ __align__(16) char SM[65536];
  int gid = blockIdx.x;
  int xcd = gid & 7;
  int s   = gid >> 3;
  int tid = threadIdx.x, lane = tid & 63, wv = tid >> 6;
  int l16 = lane & 15, quad = lane >> 4;
  int wr = (wv & 1) << 6, wc = (wv >> 1) << 6;
  const f32x4 Z4 = {0.f, 0.f, 0.f, 0.f};

  if (s < 64) {
    // ================= merged Q+K block, BK=32, 16 iters =================
    int mt_l = s >> 2, nt = s & 3;
    int mt = xcd * 16 + mt_l;
    int m0 = mt << 7, n0 = nt << 7;
    short* Asm = (short*)SM;             // [2][4096] shorts (16 KB)
    short* Bqs = (short*)(SM + 16384);   // [2][4096]
    short* Bks = (short*)(SM + 32768);   // [2][4096]

    int drow = lane >> 2;                       // 0..15 (row within 16-row op)
    int dchk = (lane & 3) ^ (drow & 3);         // source chunk (swizzled)
    const short* asrc[2];
    const short* bqsrc[2];
    const short* bksrc[2];
#pragma unroll
    for (int i = 0; i < 2; ++i) {
      int row = (wv * 2 + i) * 16 + drow;
      asrc[i]  = xb + (size_t)(m0 + row) * 512 + dchk * 8;
      bqsrc[i] = Wt + (size_t)(n0 + row) * 512 + dchk * 8;
      bksrc[i] = Wt + 262144 + (size_t)(n0 + row) * 512 + dchk * 8;
    }

    f32x4 accQ[4][4], accK[4][4];
#pragma unroll
    for (int a = 0; a < 4; ++a)
#pragma unroll
      for (int c = 0; c < 4; ++c) { accQ[a][c] = Z4; accK[a][c] = Z4; }

    // prologue: stage it=0 -> buf 0
#pragma unroll
    for (int i = 0; i < 2; ++i) {
      int g = wv * 2 + i;
      ASYNC16(asrc[i],  Asm + g * 512);
      ASYNC16(bqsrc[i], Bqs + g * 512);
      ASYNC16(bksrc[i], Bks + g * 512);
    }
    __syncthreads();

    for (int it = 0; it < 16; ++it) {
      int buf = it & 1;
      if (it < 15) {
        int k1 = (it + 1) << 5;
#pragma unroll
        for (int i = 0; i < 2; ++i) {
          int g = wv * 2 + i;
          ASYNC16(asrc[i] + k1,  Asm + (buf ^ 1) * 4096 + g * 512);
          ASYNC16(bqsrc[i] + k1, Bqs + (buf ^ 1) * 4096 + g * 512);
          ASYNC16(bksrc[i] + k1, Bks + (buf ^ 1) * 4096 + g * 512);
        }
      }
      // compute: one K=32 chunk per iter (c = quad)
      s16x8 af[4], bqf[4], bkf[4];
#pragma unroll
      for (int rb = 0; rb < 4; ++rb) {
        int row = wr + rb * 16 + l16;
        af[rb] = *(const s16x8*)(Asm + buf * 4096 + row * 32 + ((quad ^ (row & 3)) * 8));
      }
#pragma unroll
      for (int cb = 0; cb < 4; ++cb) {
        int row = wc + cb * 16 + l16;
        int off = buf * 4096 + row * 32 + ((quad ^ (row & 3)) * 8);
        bqf[cb] = *(const s16x8*)(Bqs + off);
        bkf[cb] = *(const s16x8*)(Bks + off);
      }
#pragma unroll
      for (int rb = 0; rb < 4; ++rb)
#pragma unroll
        for (int cb = 0; cb < 4; ++cb) {
          accQ[rb][cb] = __builtin_amdgcn_mfma_f32_16x16x32_bf16(af[rb], bqf[cb], accQ[rb][cb], 0, 0, 0);
          accK[rb][cb] = __builtin_amdgcn_mfma_f32_16x16x32_bf16(af[rb], bkf[cb], accK[rb][cb], 0, 0, 0);
        }
      __syncthreads();   // drains stage(it+1); final one fences SM reuse as Ct
    }

    // ---- two sequential LDS-transposed epilogues (Ct = first 32 KB of SM) ----
    short* Ct = (short*)SM;   // 128x128 bf16
    {
      float bsv[4];
#pragma unroll
      for (int cb = 0; cb < 4; ++cb) bsv[cb] = bq[n0 + wc + cb * 16 + l16];
#pragma unroll
      for (int rb = 0; rb < 4; ++rb)
#pragma unroll
        for (int cb = 0; cb < 4; ++cb)
#pragma unroll
          for (int r = 0; r < 4; ++r) {
            int m_l = wr + rb * 16 + quad * 4 + r;
            int e_l = wc + cb * 16 + l16;
            int cc  = e_l >> 3;
            Ct[m_l * 128 + ((cc ^ (m_l & 7)) * 8) + (e_l & 7)] =
                (short)f2bf(accQ[rb][cb][r] + bsv[cb]);
          }
      __syncthreads();
#pragma unroll
      for (int g = 0; g < 8; ++g) {
        int row = wv * 32 + g * 4 + (lane >> 4);
        int cc  = lane & 15;
        s16x8 v = *(const s16x8*)(Ct + row * 128 + ((cc ^ (row & 7)) * 8));
        *(s16x8*)(Qg + (size_t)(m0 + row) * 512 + n0 + cc * 8) = v;
      }
      __syncthreads();   // Ct reads done before K epilogue rewrites it
    }
    {
      float bsv[4];
#pragma unroll
      for (int cb = 0; cb < 4; ++cb) bsv[cb] = bk[n0 + wc + cb * 16 + l16];
#pragma unroll
      for (int rb = 0; rb < 4; ++rb)
#pragma unroll
        for (int cb = 0; cb < 4; ++cb)
#pragma unroll
          for (int r = 0; r < 4; ++r) {
            int m_l = wr + rb * 16 + quad * 4 + r;
            int e_l = wc + cb * 16 + l16;
            int cc  = e_l >> 3;
            Ct[m_l * 128 + ((cc ^ (m_l & 7)) * 8) + (e_l & 7)] =
                (short)f2bf(accK[rb][cb][r] + bsv[cb]);
          }
      __syncthreads();
#pragma unroll
      for (int g = 0; g < 8; ++g) {
        int row = wv * 32 + g * 4 + (lane >> 4);
        int cc  = lane & 15;
        s16x8 v = *(const s16x8*)(Ct + row * 128 + ((cc ^ (row & 7)) * 8));
        *(s16x8*)(Kg + (size_t)(m0 + row) * 512 + n0 + cc * 8) = v;
      }
    }
  } else {
    // ================= V block (R11 path, BK=64, 8 iters) =================
    int s2 = s - 64;
    int mt_l = s2 >> 2, nt = s2 & 3;
    int mt = xcd * 16 + mt_l;
    int m0 = mt << 7, n0 = nt << 7;
    const short* W = Wt + (size_t)2 * 262144;
    short* As = (short*)SM;             // [2][8192] shorts (32 KB)
    short* Bs = (short*)(SM + 32768);   // [2][8192]

    int drow = lane >> 3;
    int dchk = (lane & 7) ^ drow;
    const short* asrc[4];
    const short* bsrc[4];
#pragma unroll
    for (int i = 0; i < 4; ++i) {
      int row = (wv * 4 + i) * 8 + drow;
      asrc[i] = xb + (size_t)(m0 + row) * 512 + dchk * 8;
      bsrc[i] = W  + (size_t)(n0 + row) * 512 + dchk * 8;
    }

    f32x4 acc[4][4];
#pragma unroll
    for (int a = 0; a < 4; ++a)
#pragma unroll
      for (int c = 0; c < 4; ++c) acc[a][c] = Z4;

#pragma unroll
    for (int i = 0; i < 4; ++i) {
      int g = wv * 4 + i;
      ASYNC16(asrc[i], As + g * 512);
      ASYNC16(bsrc[i], Bs + g * 512);
    }
    __syncthreads();

    for (int it = 0; it < 8; ++it) {
      int buf = it & 1;
      if (it < 7) {
        int k1 = (it + 1) << 6;
#pragma unroll
        for (int i = 0; i < 4; ++i) {
          int g = wv * 4 + i;
          ASYNC16(asrc[i] + k1, As + (buf ^ 1) * 8192 + g * 512);
          ASYNC16(bsrc[i] + k1, Bs + (buf ^ 1) * 8192 + g * 512);
        }
      }
#pragma unroll
      for (int kk = 0; kk < 2; ++kk) {
        s16x8 af[4], bfr[4];
#pragma unroll
        for (int rb = 0; rb < 4; ++rb) {
          int row = wr + rb * 16 + l16;
          int c   = kk * 4 + quad;
          af[rb] = *(const s16x8*)(As + buf * 8192 + row * 64 + ((c ^ (row & 7)) * 8));
        }
#pragma unroll
        for (int cb = 0; cb < 4; ++cb) {
          int row = wc + cb * 16 + l16;
          int c   = kk * 4 + quad;
          bfr[cb] = *(const s16x8*)(Bs + buf * 8192 + row * 64 + ((c ^ (row & 7)) * 8));
        }
#pragma unroll
        for (int rb = 0; rb < 4; ++rb)
#pragma unroll
          for (int cb = 0; cb < 4; ++cb)
            acc[rb][cb] = __builtin_amdgcn_mfma_f32_16x16x32_bf16(af[rb], bfr[cb], acc[rb][cb], 0, 0, 0);
      }
      __syncthreads();
    }

    float bsv[4];
#pragma unroll
    for (int cb = 0; cb < 4; ++cb) bsv[cb] = bv[n0 + wc + cb * 16 + l16];
#pragma unroll
    for (int rb = 0; rb < 4; ++rb)
#pragma unroll
      for (int cb = 0; cb < 4; ++cb) {
        u16x4 h;
#pragma unroll
        for (int r = 0; r < 4; ++r) h[r] = f2bf(acc[rb][cb][r] + bsv[cb]);
        int m  = m0 + wr + rb * 16 + quad * 4;
        int bb = m >> 11, sl = m & 2047;
        int e  = n0 + wc + cb * 16 + l16;
        size_t idx = ((((size_t)bb * 32 + (e >> 4)) * 64 + (sl >> 5)) * 16 +
                      (e & 15)) * 32 + (sl & 31);
        *(u16x4*)(VTg + idx) = h;
      }
  }
}

// ---------------- kernel 3: flash attention v9 (UNCHANGED, 98.2-100.5 µs control) ----------------
__global__ __launch_bounds__(512, 2) void attn_kernel(
    const short* __restrict__ Qg, const short* __restrict__ Kg,
    const short* __restrict__ VTg, float* __restrict__ out) {
  __shared__ __align__(16) short Kt[3][32 * 512];   // 96 KB triple buffer
  __shared__ __align__(16) short Pl[2][64 * 40];    // 10 KB double buffer
  __shared__ float l_l[64];
  const float SCL2 = 0.06375871855f;  // log2(e)/sqrt(512)

  int b = blockIdx.x & 7, qt = blockIdx.x >> 3;   // qt 0..31
  int s0 = qt << 6;                                // 64 rows/block
  int rot = (qt << 1) & 63;                        // per-block tile phase
  int tid = threadIdx.x, lane = tid & 63, wv = tid >> 6;  // wv 0..7
  int l16 = lane & 15, quad = lane >> 4;

  const short* Kb = Kg  + (size_t)b * S_LEN * 512;
  const short* Vb = VTg + (size_t)b * 1048576;     // [32 et][64 st][16][32]

  const short* kdma[4];
#pragma unroll
  for (int i = 0; i < 4; ++i) {
    int r = wv * 4 + i;
    kdma[i] = Kb + (size_t)r * 512 + ((lane ^ (r & 7)) * 8);
  }

  {
    size_t a0 = (size_t)rot * 16384;
    size_t a1 = (size_t)((rot + 1) & 63) * 16384;
#pragma unroll
    for (int i = 0; i < 4; ++i)
      ASYNC16(kdma[i] + a0, &Kt[0][(wv * 4 + i) * 512]);
#pragma unroll
    for (int i = 0; i < 4; ++i)
      ASYNC16(kdma[i] + a1, &Kt[1][(wv * 4 + i) * 512]);
  }

  if (wv < 4) {
    // ================= QK producer branch =================
    int a = wv & 1, h = wv >> 1;
    const short* qrowA = Qg + ((size_t)b * S_LEN + s0 + a * 32 + l16) * 512 + quad * 8;
    const short* qrowB = qrowA + (size_t)16 * 512;
    s16x8 qfA[16], qfB[16];
#pragma unroll
    for (int c = 0; c < 16; ++c) {
      qfA[c] = *(const s16x8*)(qrowA + c * 32);
      qfB[c] = *(const s16x8*)(qrowB + c * 32);
    }
    const f32x4 Z4 = {0.f, 0.f, 0.f, 0.f};
    f32x4 lsumA = Z4, lsumB = Z4;

    __syncthreads();   // prologue drain  [barrier #0]

    for (int kt = 0; kt < 64; ++kt) {
      int rbuf = kt % 3, wbuf = (kt + 2) % 3;
      {
        size_t adv = (size_t)((kt + 2 + rot) & 63) * 16384;
#pragma unroll
        for (int i = 0; i < 4; ++i)
          ASYNC16(kdma[i] + adv, &Kt[wbuf][(wv * 4 + i) * 512]);
      }
      __builtin_amdgcn_sched_barrier(0);

      f32x4 sA = Z4, sB = Z4;
      int krow = h * 16 + l16;
      const short* kb = &Kt[rbuf][krow * 512];
      int ksw = krow & 7;
      __builtin_amdgcn_s_setprio(1);
#pragma unroll
      for (int c = 0; c < 16; ++c) {
        s16x8 kf = *(const s16x8*)(kb + (((c * 4 + quad) ^ ksw) * 8));
        sA = __builtin_amdgcn_mfma_f32_16x16x32_bf16(qfA[c], kf, sA, 0, 0, 0);
        sB = __builtin_amdgcn_mfma_f32_16x16x32_bf16(qfB[c], kf, sB, 0, 0, 0);
      }
      __builtin_amdgcn_s_setprio(0);

      short* Pc = Pl[kt & 1];
#pragma unroll
      for (int r = 0; r < 4; ++r) {
        float pA = exp2f(sA[r] * SCL2);
        lsumA[r] += pA;
        Pc[(a * 32 + quad * 4 + r) * 40 + h * 16 + l16] = (short)f2bf(pA);
        float pB = exp2f(sB[r] * SCL2);
        lsumB[r] += pB;
        Pc[(a * 32 + 16 + quad * 4 + r) * 40 + h * 16 + l16] = (short)f2bf(pB);
      }

      asm volatile("s_waitcnt vmcnt(4) lgkmcnt(0)\n\ts_barrier" ::: "memory");
      __builtin_amdgcn_sched_barrier(0);
    }

#pragma unroll
    for (int r = 0; r < 4; ++r) {
      float vA = lsumA[r];
      vA += __shfl_xor(vA, 1); vA += __shfl_xor(vA, 2);
      vA += __shfl_xor(vA, 4); vA += __shfl_xor(vA, 8);
      lsumA[r] = vA;
      float vB = lsumB[r];
      vB += __shfl_xor(vB, 1); vB += __shfl_xor(vB, 2);
      vB += __shfl_xor(vB, 4); vB += __shfl_xor(vB, 8);
      lsumB[r] = vB;
    }
    if (h == 0 && l16 == 0) {
#pragma unroll
      for (int r = 0; r < 4; ++r) {
        l_l[a * 32 + quad * 4 + r]      = lsumA[r];
        l_l[a * 32 + 16 + quad * 4 + r] = lsumB[r];
      }
    }
    __syncthreads();   // epilogue barrier #1
    if (h == 1 && l16 == 0) {
#pragma unroll
      for (int r = 0; r < 4; ++r) {
        l_l[a * 32 + quad * 4 + r]      += lsumA[r];
        l_l[a * 32 + 16 + quad * 4 + r] += lsumB[r];
      }
    }
    __syncthreads();   // epilogue barrier #2
  } else {
    // ================= PV consumer branch =================
    int pw = wv - 4;
    int e0 = pw << 7;
    const short* vbase = Vb + (size_t)pw * 262144 + l16 * 32 + quad * 8;

    const f32x4 Z4 = {0.f, 0.f, 0.f, 0.f};
    f32x4 acc[4][8];
#pragma unroll
    for (int g = 0; g < 4; ++g)
#pragma unroll
      for (int cb = 0; cb < 8; ++cb) acc[g][cb] = Z4;
    s16x8 vfA[8], vfB[8];

    __syncthreads();   // prologue drain  [barrier #0]

    for (int kt = 0; kt < 64; kt += 2) {
      {
        size_t adv = (size_t)((kt + 2 + rot) & 63) * 16384;
        int wbuf = (kt + 2) % 3;
#pragma unroll
        for (int i = 0; i < 4; ++i)
          ASYNC16(kdma[i] + adv, &Kt[wbuf][(wv * 4 + i) * 512]);
      }
      {
        size_t vadv = (size_t)((kt + rot) & 63) * 512;
#pragma unroll
        for (int cb = 0; cb < 8; ++cb)
          vfA[cb] = *(const s16x8*)(vbase + (size_t)cb * 32768 + vadv);
      }
      if (kt) {
        s16x8 pf[4];
#pragma unroll
        for (int g = 0; g < 4; ++g)
          pf[g] = *(const s16x8*)(&Pl[1][(g * 16 + l16) * 40 + quad * 8]);
        __builtin_amdgcn_s_setprio(1);
#pragma unroll
        for (int cb = 0; cb < 8; ++cb)
#pragma unroll
          for (int g = 0; g < 4; ++g)
            acc[g][cb] = __builtin_amdgcn_mfma_f32_16x16x32_bf16(pf[g], vfB[cb], acc[g][cb], 0, 0, 0);
        __builtin_amdgcn_s_setprio(0);
      }
      asm volatile("s_waitcnt lgkmcnt(0)\n\ts_barrier" ::: "memory");
      __builtin_amdgcn_sched_barrier(0);

      {
        size_t adv = (size_t)((kt + 3 + rot) & 63) * 16384;
        int wbuf = (kt + 3) % 3;
#pragma unroll
        for (int i = 0; i < 4; ++i)
          ASYNC16(kdma[i] + adv, &Kt[wbuf][(wv * 4 + i) * 512]);
      }
      {
        size_t vadv = (size_t)((kt + 1 + rot) & 63) * 512;
#pragma unroll
        for (int cb = 0; cb < 8; ++cb)
          vfB[cb] = *(const s16x8*)(vbase + (size_t)cb * 32768 + vadv);
      }
      {
        s16x8 pf[4];
#pragma unroll
        for (int g = 0; g < 4; ++g)
          pf[g] = *(const s16x8*)(&Pl[0][(g * 16 + l16) * 40 + quad * 8]);
        __builtin_amdgcn_s_setprio(1);
#pragma unroll
        for (int cb = 0; cb < 8; ++cb)
#pragma unroll
          for (int g = 0; g < 4; ++g)
            acc[g][cb] = __builtin_amdgcn_mfma_f32_16x16x32_bf16(pf[g], vfA[cb], acc[g][cb], 0, 0, 0);
        __builtin_amdgcn_s_setprio(0);
      }
      asm volatile("s_waitcnt lgkmcnt(0)\n\ts_barrier" ::: "memory");
      __builtin_amdgcn_sched_barrier(0);
    }

    asm volatile("s_waitcnt vmcnt(0)" ::: "memory");
    __builtin_amdgcn_sched_barrier(0);
    {
      s16x8 pf[4];
#pragma unroll
      for (int g = 0; g < 4; ++g)
        pf[g] = *(const s16x8*)(&Pl[1][(g * 16 + l16) * 40 + quad * 8]);
#pragma unroll
      for (int cb = 0; cb < 8; ++cb)
#pragma unroll
        for (int g = 0; g < 4; ++g)
          acc[g][cb] = __builtin_amdgcn_mfma_f32_16x16x32_bf16(pf[g], vfB[cb], acc[g][cb], 0, 0, 0);
    }
    __syncthreads();   // epilogue barrier #1
    __syncthreads();   // epilogue barrier #2

#pragma unroll
    for (int g = 0; g < 4; ++g) {
      f32x4 lv = *(const f32x4*)(l_l + g * 16 + quad * 4);
      f32x4 li;
#pragma unroll
      for (int r = 0; r < 4; ++r) li[r] = 1.0f / lv[r];
#pragma unroll
      for (int cb = 0; cb < 8; ++cb)
#pragma unroll
        for (int r = 0; r < 4; ++r)
          out[((size_t)b * S_LEN + s0 + g * 16 + quad * 4 + r) * 512 + e0 + cb * 16 + l16] =
              acc[g][cb][r] * li[r];
    }
  }
}

// ---------------- host launch ----------------
extern "C" void kernel_launch(void* const* d_in, const int* in_sizes, int n_in,
                              void* d_out, int out_size, void* d_ws, size_t ws_size,
                              hipStream_t stream) {
  const float* x  = (const float*)d_in[0];
  const float* Wq = (const float*)d_in[1];
  const float* bq = (const float*)d_in[2];
  const float* Wk = (const float*)d_in[3];
  const float* bk = (const float*)d_in[4];
  const float* Wv = (const float*)d_in[5];
  const float* bv = (const float*)d_in[6];

  short* Wt  = (short*)d_ws;
  short* xb  = (short*)((char*)d_ws + 1572864);
  short* Qg  = xb + (size_t)8388608;
  short* Kg  = Qg + (size_t)8388608;
  short* VTg = Kg + (size_t)8388608;

  xconv_kernel<<<4096, 256, 0, stream>>>(x, xb);
  wconv_kernel<<<192, 256, 0, stream>>>(Wq, Wk, Wv, Wt);
  qkv_gemm<<<1024, 256, 0, stream>>>(xb, Wt, bq, bk, bv, Qg, Kg, VTg);
  attn_kernel<<<256, 512, 0, stream>>>(Qg, Kg, VTg, (float*)d_out);
}

// Round 17
// 213.725 us; speedup vs baseline: 1.0518x; 1.0518x over previous
//
#include <hip/hip_runtime.h>
#include <stdint.h>

// Self-attention, B=8 S=2048 D=E=512, fp32 in/out, bf16 MFMA internally.
// FINAL: session-best configuration (R11, 212.47 µs; re-measured R15 214.2).
//   xconv: x fp32 -> bf16 (vectorized)
//   wconv: W[k][n] fp32 -> Wt[n][k] bf16 (x3), LDS-tiled transpose
//   qkv: pipelined double-buffered DMA staging + XCD-pinned m-partitioning
//        + LDS-transposed coalesced Q/K epilogue (BK=64; merged-QK and BK=32
//        variants measured slower)
//   attn v9: producer/consumer wave split (QK waves 32rx16k kf-dedup; PV waves
//        e-slice 128), Kt triple-buffered counted-vmcnt DMA, Pl dbuf,
//        1 fused barrier/iter, per-block K-tile rotation, XCD pinning.
//        5-round control: 98.2-100.5 µs, MfmaUtil 28.3-29.4, conflicts 5.24e6.

using f32x4 = __attribute__((ext_vector_type(4))) float;
using s16x8 = __attribute__((ext_vector_type(8))) short;
using u16x4 = __attribute__((ext_vector_type(4))) unsigned short;

#define S_LEN 2048
#define EMB   512

#define ASYNC16(g, l)                                                     \
  __builtin_amdgcn_global_load_lds(                                       \
      (const __attribute__((address_space(1))) void*)(g),                 \
      (__attribute__((address_space(3))) void*)(l), 16, 0, 0)

__device__ __forceinline__ unsigned short f2bf(float f) {
  union { float f; unsigned u; } v; v.f = f;
  unsigned r = v.u + 0x7fffu + ((v.u >> 16) & 1u);   // RNE
  return (unsigned short)(r >> 16);
}

// ---------------- kernel 0: x fp32 -> bf16 ----------------
__global__ __launch_bounds__(256) void xconv_kernel(
    const float* __restrict__ x, short* __restrict__ xb) {
  int i = (blockIdx.x * 256 + threadIdx.x) * 8;
  f32x4 a = *(const f32x4*)(x + i);
  f32x4 b = *(const f32x4*)(x + i + 4);
  s16x8 h;
  h[0] = (short)f2bf(a[0]); h[1] = (short)f2bf(a[1]);
  h[2] = (short)f2bf(a[2]); h[3] = (short)f2bf(a[3]);
  h[4] = (short)f2bf(b[0]); h[5] = (short)f2bf(b[1]);
  h[6] = (short)f2bf(b[2]); h[7] = (short)f2bf(b[3]);
  *(s16x8*)(xb + i) = h;
}

// ---------------- kernel 1: weight transpose (LDS-tiled, coalesced) ----------------
__global__ __launch_bounds__(256) void wconv_kernel(
    const float* __restrict__ Wq, const float* __restrict__ Wk,
    const float* __restrict__ Wv, short* __restrict__ Wt) {
  __shared__ float T[64][65];
  int bid = blockIdx.x;
  int mat = bid >> 6;
  int t   = bid & 63;
  int k0  = (t & 7) << 6, n0 = (t >> 3) << 6;
  const float* W = (mat == 0) ? Wq : (mat == 1) ? Wk : Wv;
  int tid = threadIdx.x;
  int rr = tid >> 4, cc = tid & 15;
#pragma unroll
  for (int p = 0; p < 4; ++p) {
    int row = p * 16 + rr;
    f32x4 v = *(const f32x4*)(W + (size_t)(k0 + row) * 512 + n0 + cc * 4);
#pragma unroll
    for (int j = 0; j < 4; ++j) T[row][cc * 4 + j] = v[j];
  }
  __syncthreads();
  short* D = Wt + (size_t)mat * 262144;
#pragma unroll
  for (int p = 0; p < 4; ++p) {
    int nrow = p * 16 + rr;
    u16x4 h;
#pragma unroll
    for (int j = 0; j < 4; ++j) h[j] = f2bf(T[cc * 4 + j][nrow]);
    *(u16x4*)(D + (size_t)(n0 + nrow) * 512 + k0 + cc * 4) = h;
  }
}

// ---------------- kernel 2: QKV projection GEMM (pipelined + XCD-pinned + LDS epilogue) ----------------
__global__ __launch_bounds__(256) void qkv_gemm(
    const short* __restrict__ xb, const short* __restrict__ Wt,
    const float* __restrict__ bq, const float* __restrict__ bk,
    const float* __restrict__ bv,
    short* __restrict__ Qg, short* __restrict__ Kg, short* __restrict__ VTg) {
  __shared__ __align__(16) short As[2][128 * 64];
  __shared__ __align__(16) short Bs[2][128 * 64];
  int gid = blockIdx.x;
  int xcd = gid & 7;
  int s   = gid >> 3;
  int mt_l = s / 12;
  int j    = s - mt_l * 12;
  int mat  = j >> 2;
  int nt   = j & 3;
  int mt   = xcd * 16 + mt_l;
  int m0   = mt << 7, n0 = nt << 7;
  const short* W    = Wt + (size_t)mat * 262144;
  const float* bias = (mat == 0) ? bq : (mat == 1) ? bk : bv;

  int tid = threadIdx.x, lane = tid & 63, wv = tid >> 6;
  int l16 = lane & 15, quad = lane >> 4;
  int wr = (wv & 1) << 6, wc = (wv >> 1) << 6;
  int drow = lane >> 3;
  int dchk = (lane & 7) ^ drow;

  const short* asrc[4];
  const short* bsrc[4];
#pragma unroll
  for (int i = 0; i < 4; ++i) {
    int row = (wv * 4 + i) * 8 + drow;
    asrc[i] = xb + (size_t)(m0 + row) * 512 + dchk * 8;
    bsrc[i] = W  + (size_t)(n0 + row) * 512 + dchk * 8;
  }

  const f32x4 Z4 = {0.f, 0.f, 0.f, 0.f};
  f32x4 acc[4][4];
#pragma unroll
  for (int a = 0; a < 4; ++a)
#pragma unroll
    for (int c = 0; c < 4; ++c) acc[a][c] = Z4;

#pragma unroll
  for (int i = 0; i < 4; ++i) {
    int g = wv * 4 + i;
    ASYNC16(asrc[i], &As[0][g * 512]);
    ASYNC16(bsrc[i], &Bs[0][g * 512]);
  }
  __syncthreads();

  for (int it = 0; it < 8; ++it) {
    int buf = it & 1;
    if (it < 7) {
      int k1 = (it + 1) << 6;
#pragma unroll
      for (int i = 0; i < 4; ++i) {
        int g = wv * 4 + i;
        ASYNC16(asrc[i] + k1, &As[buf ^ 1][g * 512]);
        ASYNC16(bsrc[i] + k1, &Bs[buf ^ 1][g * 512]);
      }
    }
#pragma unroll
    for (int kk = 0; kk < 2; ++kk) {
      s16x8 af[4], bfr[4];
#pragma unroll
      for (int rb = 0; rb < 4; ++rb) {
        int row = wr + rb * 16 + l16;
        int c   = kk * 4 + quad;
        af[rb] = *(const s16x8*)(&As[buf][row * 64 + ((c ^ (row & 7)) * 8)]);
      }
#pragma unroll
      for (int cb = 0; cb < 4; ++cb) {
        int row = wc + cb * 16 + l16;
        int c   = kk * 4 + quad;
        bfr[cb] = *(const s16x8*)(&Bs[buf][row * 64 + ((c ^ (row & 7)) * 8)]);
      }
#pragma unroll
      for (int rb = 0; rb < 4; ++rb)
#pragma unroll
        for (int cb = 0; cb < 4; ++cb)
          acc[rb][cb] = __builtin_amdgcn_mfma_f32_16x16x32_bf16(af[rb], bfr[cb], acc[rb][cb], 0, 0, 0);
    }
    __syncthreads();   // final iter's barrier also fences As reads before Ct reuse
  }

  float bsv[4];
#pragma unroll
  for (int cb = 0; cb < 4; ++cb) bsv[cb] = bias[n0 + wc + cb * 16 + l16];

  if (mat < 2) {
    // LDS-transposed epilogue: acc -> swizzled 128x128 bf16 tile in dead As,
    // then coalesced s16x8 stores (256B full-line segments).
    short* D  = (mat == 0) ? Qg : Kg;
    short* Ct = &As[0][0];   // 32 KB, exactly 128x128 bf16
#pragma unroll
    for (int rb = 0; rb < 4; ++rb)
#pragma unroll
      for (int cb = 0; cb < 4; ++cb)
#pragma unroll
        for (int r = 0; r < 4; ++r) {
          int m_l = wr + rb * 16 + quad * 4 + r;
          int e_l = wc + cb * 16 + l16;
          int cc  = e_l >> 3;
          Ct[m_l * 128 + ((cc ^ (m_l & 7)) * 8) + (e_l & 7)] =
              (short)f2bf(acc[rb][cb][r] + bsv[cb]);
        }
    __syncthreads();
#pragma unroll
    for (int g = 0; g < 8; ++g) {
      int row = wv * 32 + g * 4 + (lane >> 4);
      int cc  = lane & 15;
      s16x8 v = *(const s16x8*)(Ct + row * 128 + ((cc ^ (row & 7)) * 8));
      *(s16x8*)(D + (size_t)(m0 + row) * 512 + n0 + cc * 8) = v;
    }
  } else {
    // V: tiled transpose layout [bb][e>>4][s>>5][e&15][s&31], 1KB tiles
#pragma unroll
    for (int rb = 0; rb < 4; ++rb)
#pragma unroll
      for (int cb = 0; cb < 4; ++cb) {
        u16x4 h;
#pragma unroll
        for (int r = 0; r < 4; ++r) h[r] = f2bf(acc[rb][cb][r] + bsv[cb]);
        int m  = m0 + wr + rb * 16 + quad * 4;
        int bb = m >> 11, sl = m & 2047;
        int e  = n0 + wc + cb * 16 + l16;
        size_t idx = ((((size_t)bb * 32 + (e >> 4)) * 64 + (sl >> 5)) * 16 +
                      (e & 15)) * 32 + (sl & 31);
        *(u16x4*)(VTg + idx) = h;
      }
  }
}

// ---------------- kernel 3: flash attention v9 (producer/consumer + rotation) ----------------
__global__ __launch_bounds__(512, 2) void attn_kernel(
    const short* __restrict__ Qg, const short* __restrict__ Kg,
    const short* __restrict__ VTg, float* __restrict__ out) {
  __shared__ __align__(16) short Kt[3][32 * 512];   // 96 KB triple buffer
  __shared__ __align__(16) short Pl[2][64 * 40];    // 10 KB double buffer
  __shared__ float l_l[64];
  const float SCL2 = 0.06375871855f;  // log2(e)/sqrt(512)

  int b = blockIdx.x & 7, qt = blockIdx.x >> 3;   // qt 0..31
  int s0 = qt << 6;                                // 64 rows/block
  int rot = (qt << 1) & 63;                        // per-block tile phase
  int tid = threadIdx.x, lane = tid & 63, wv = tid >> 6;  // wv 0..7
  int l16 = lane & 15, quad = lane >> 4;

  const short* Kb = Kg  + (size_t)b * S_LEN * 512;
  const short* Vb = VTg + (size_t)b * 1048576;     // [32 et][64 st][16][32]

  const short* kdma[4];
#pragma unroll
  for (int i = 0; i < 4; ++i) {
    int r = wv * 4 + i;
    kdma[i] = Kb + (size_t)r * 512 + ((lane ^ (r & 7)) * 8);
  }

  {
    size_t a0 = (size_t)rot * 16384;
    size_t a1 = (size_t)((rot + 1) & 63) * 16384;
#pragma unroll
    for (int i = 0; i < 4; ++i)
      ASYNC16(kdma[i] + a0, &Kt[0][(wv * 4 + i) * 512]);
#pragma unroll
    for (int i = 0; i < 4; ++i)
      ASYNC16(kdma[i] + a1, &Kt[1][(wv * 4 + i) * 512]);
  }

  if (wv < 4) {
    // ================= QK producer branch =================
    int a = wv & 1, h = wv >> 1;
    const short* qrowA = Qg + ((size_t)b * S_LEN + s0 + a * 32 + l16) * 512 + quad * 8;
    const short* qrowB = qrowA + (size_t)16 * 512;
    s16x8 qfA[16], qfB[16];
#pragma unroll
    for (int c = 0; c < 16; ++c) {
      qfA[c] = *(const s16x8*)(qrowA + c * 32);
      qfB[c] = *(const s16x8*)(qrowB + c * 32);
    }
    const f32x4 Z4 = {0.f, 0.f, 0.f, 0.f};
    f32x4 lsumA = Z4, lsumB = Z4;

    __syncthreads();   // prologue drain  [barrier #0]

    for (int kt = 0; kt < 64; ++kt) {
      int rbuf = kt % 3, wbuf = (kt + 2) % 3;
      {
        size_t adv = (size_t)((kt + 2 + rot) & 63) * 16384;
#pragma unroll
        for (int i = 0; i < 4; ++i)
          ASYNC16(kdma[i] + adv, &Kt[wbuf][(wv * 4 + i) * 512]);
      }
      __builtin_amdgcn_sched_barrier(0);

      f32x4 sA = Z4, sB = Z4;
      int krow = h * 16 + l16;
      const short* kb = &Kt[rbuf][krow * 512];
      int ksw = krow & 7;
      __builtin_amdgcn_s_setprio(1);
#pragma unroll
      for (int c = 0; c < 16; ++c) {
        s16x8 kf = *(const s16x8*)(kb + (((c * 4 + quad) ^ ksw) * 8));
        sA = __builtin_amdgcn_mfma_f32_16x16x32_bf16(qfA[c], kf, sA, 0, 0, 0);
        sB = __builtin_amdgcn_mfma_f32_16x16x32_bf16(qfB[c], kf, sB, 0, 0, 0);
      }
      __builtin_amdgcn_s_setprio(0);

      short* Pc = Pl[kt & 1];
#pragma unroll
      for (int r = 0; r < 4; ++r) {
        float pA = exp2f(sA[r] * SCL2);
        lsumA[r] += pA;
        Pc[(a * 32 + quad * 4 + r) * 40 + h * 16 + l16] = (short)f2bf(pA);
        float pB = exp2f(sB[r] * SCL2);
        lsumB[r] += pB;
        Pc[(a * 32 + 16 + quad * 4 + r) * 40 + h * 16 + l16] = (short)f2bf(pB);
      }

      asm volatile("s_waitcnt vmcnt(4) lgkmcnt(0)\n\ts_barrier" ::: "memory");
      __builtin_amdgcn_sched_barrier(0);
    }

#pragma unroll
    for (int r = 0; r < 4; ++r) {
      float vA = lsumA[r];
      vA += __shfl_xor(vA, 1); vA += __shfl_xor(vA, 2);
      vA += __shfl_xor(vA, 4); vA += __shfl_xor(vA, 8);
      lsumA[r] = vA;
      float vB = lsumB[r];
      vB += __shfl_xor(vB, 1); vB += __shfl_xor(vB, 2);
      vB += __shfl_xor(vB, 4); vB += __shfl_xor(vB, 8);
      lsumB[r] = vB;
    }
    if (h == 0 && l16 == 0) {
#pragma unroll
      for (int r = 0; r < 4; ++r) {
        l_l[a * 32 + quad * 4 + r]      = lsumA[r];
        l_l[a * 32 + 16 + quad * 4 + r] = lsumB[r];
      }
    }
    __syncthreads();   // epilogue barrier #1
    if (h == 1 && l16 == 0) {
#pragma unroll
      for (int r = 0; r < 4; ++r) {
        l_l[a * 32 + quad * 4 + r]      += lsumA[r];
        l_l[a * 32 + 16 + quad * 4 + r] += lsumB[r];
      }
    }
    __syncthreads();   // epilogue barrier #2
  } else {
    // ================= PV consumer branch =================
    int pw = wv - 4;
    int e0 = pw << 7;
    const short* vbase = Vb + (size_t)pw * 262144 + l16 * 32 + quad * 8;

    const f32x4 Z4 = {0.f, 0.f, 0.f, 0.f};
    f32x4 acc[4][8];
#pragma unroll
    for (int g = 0; g < 4; ++g)
#pragma unroll
      for (int cb = 0; cb < 8; ++cb) acc[g][cb] = Z4;
    s16x8 vfA[8], vfB[8];

    __syncthreads();   // prologue drain  [barrier #0]

    for (int kt = 0; kt < 64; kt += 2) {
      {
        size_t adv = (size_t)((kt + 2 + rot) & 63) * 16384;
        int wbuf = (kt + 2) % 3;
#pragma unroll
        for (int i = 0; i < 4; ++i)
          ASYNC16(kdma[i] + adv, &Kt[wbuf][(wv * 4 + i) * 512]);
      }
      {
        size_t vadv = (size_t)((kt + rot) & 63) * 512;
#pragma unroll
        for (int cb = 0; cb < 8; ++cb)
          vfA[cb] = *(const s16x8*)(vbase + (size_t)cb * 32768 + vadv);
      }
      if (kt) {
        s16x8 pf[4];
#pragma unroll
        for (int g = 0; g < 4; ++g)
          pf[g] = *(const s16x8*)(&Pl[1][(g * 16 + l16) * 40 + quad * 8]);
        __builtin_amdgcn_s_setprio(1);
#pragma unroll
        for (int cb = 0; cb < 8; ++cb)
#pragma unroll
          for (int g = 0; g < 4; ++g)
            acc[g][cb] = __builtin_amdgcn_mfma_f32_16x16x32_bf16(pf[g], vfB[cb], acc[g][cb], 0, 0, 0);
        __builtin_amdgcn_s_setprio(0);
      }
      asm volatile("s_waitcnt lgkmcnt(0)\n\ts_barrier" ::: "memory");
      __builtin_amdgcn_sched_barrier(0);

      {
        size_t adv = (size_t)((kt + 3 + rot) & 63) * 16384;
        int wbuf = (kt + 3) % 3;
#pragma unroll
        for (int i = 0; i < 4; ++i)
          ASYNC16(kdma[i] + adv, &Kt[wbuf][(wv * 4 + i) * 512]);
      }
      {
        size_t vadv = (size_t)((kt + 1 + rot) & 63) * 512;
#pragma unroll
        for (int cb = 0; cb < 8; ++cb)
          vfB[cb] = *(const s16x8*)(vbase + (size_t)cb * 32768 + vadv);
      }
      {
        s16x8 pf[4];
#pragma unroll
        for (int g = 0; g < 4; ++g)
          pf[g] = *(const s16x8*)(&Pl[0][(g * 16 + l16) * 40 + quad * 8]);
        __builtin_amdgcn_s_setprio(1);
#pragma unroll
        for (int cb = 0; cb < 8; ++cb)
#pragma unroll
          for (int g = 0; g < 4; ++g)
            acc[g][cb] = __builtin_amdgcn_mfma_f32_16x16x32_bf16(pf[g], vfA[cb], acc[g][cb], 0, 0, 0);
        __builtin_amdgcn_s_setprio(0);
      }
      asm volatile("s_waitcnt lgkmcnt(0)\n\ts_barrier" ::: "memory");
      __builtin_amdgcn_sched_barrier(0);
    }

    asm volatile("s_waitcnt vmcnt(0)" ::: "memory");
    __builtin_amdgcn_sched_barrier(0);
    {
      s16x8 pf[4];
#pragma unroll
      for (int g = 0; g < 4; ++g)
        pf[g] = *(const s16x8*)(&Pl[1][(g * 16 + l16) * 40 + quad * 8]);
#pragma unroll
      for (int cb = 0; cb < 8; ++cb)
#pragma unroll
        for (int g = 0; g < 4; ++g)
          acc[g][cb] = __builtin_amdgcn_mfma_f32_16x16x32_bf16(pf[g], vfB[cb], acc[g][cb], 0, 0, 0);
    }
    __syncthreads();   // epilogue barrier #1
    __syncthreads();   // epilogue barrier #2

#pragma unroll
    for (int g = 0; g < 4; ++g) {
      f32x4 lv = *(const f32x4*)(l_l + g * 16 + quad * 4);
      f32x4 li;
#pragma unroll
      for (int r = 0; r < 4; ++r) li[r] = 1.0f / lv[r];
#pragma unroll
      for (int cb = 0; cb < 8; ++cb)
#pragma unroll
        for (int r = 0; r < 4; ++r)
          out[((size_t)b * S_LEN + s0 + g * 16 + quad * 4 + r) * 512 + e0 + cb * 16 + l16] =
              acc[g][cb][r] * li[r];
    }
  }
}

// ---------------- host launch ----------------
extern "C" void kernel_launch(void* const* d_in, const int* in_sizes, int n_in,
                              void* d_out, int out_size, void* d_ws, size_t ws_size,
                              hipStream_t stream) {
  const float* x  = (const float*)d_in[0];
  const float* Wq = (const float*)d_in[1];
  const float* bq = (const float*)d_in[2];
  const float* Wk = (const float*)d_in[3];
  const float* bk = (const float*)d_in[4];
  const float* Wv = (const float*)d_in[5];
  const float* bv = (const float*)d_in[6];

  short* Wt  = (short*)d_ws;
  short* xb  = (short*)((char*)d_ws + 1572864);
  short* Qg  = xb + (size_t)8388608;
  short* Kg  = Qg + (size_t)8388608;
  short* VTg = Kg + (size_t)8388608;

  xconv_kernel<<<4096, 256, 0, stream>>>(x, xb);
  wconv_kernel<<<192, 256, 0, stream>>>(Wq, Wk, Wv, Wt);
  qkv_gemm<<<1536, 256, 0, stream>>>(xb, Wt, bq, bk, bv, Qg, Kg, VTg);
  attn_kernel<<<256, 512, 0, stream>>>(Qg, Kg, VTg, (float*)d_out);
}

// Round 18
// 211.937 us; speedup vs baseline: 1.0607x; 1.0084x over previous
//
#include <hip/hip_runtime.h>
#include <stdint.h>

// Self-attention, B=8 S=2048 D=E=512, fp32 in/out, bf16 MFMA internally.
// Session-best (R11/R15/R17: 212.5-214.2 µs) + R7's proven conv-launch fusion:
//   conv:  ONE kernel, 4288 blocks: blk<4096 -> x fp32->bf16; else W transpose.
//   qkv:   pipelined double-buffered DMA staging + XCD-pinned m-partitioning
//          + LDS-transposed coalesced Q/K epilogue (BK=64).
//   attn v9: producer/consumer wave split (QK waves 32rx16k kf-dedup; PV waves
//          e-slice 128), Kt triple-buffered counted-vmcnt DMA, Pl dbuf,
//          1 fused barrier/iter, per-block K-tile rotation, XCD pinning.
//          6-round control: 98.2-100.5 µs, MfmaUtil 28.3-29.4, conflicts 5.24e6.

using f32x4 = __attribute__((ext_vector_type(4))) float;
using s16x8 = __attribute__((ext_vector_type(8))) short;
using u16x4 = __attribute__((ext_vector_type(4))) unsigned short;

#define S_LEN 2048
#define EMB   512

#define ASYNC16(g, l)                                                     \
  __builtin_amdgcn_global_load_lds(                                       \
      (const __attribute__((address_space(1))) void*)(g),                 \
      (__attribute__((address_space(3))) void*)(l), 16, 0, 0)

__device__ __forceinline__ unsigned short f2bf(float f) {
  union { float f; unsigned u; } v; v.f = f;
  unsigned r = v.u + 0x7fffu + ((v.u >> 16) & 1u);   // RNE
  return (unsigned short)(r >> 16);
}

// ---------------- kernel 0: fused x-convert + W-transpose (R7, proven) ----------------
__global__ __launch_bounds__(256) void conv_kernel(
    const float* __restrict__ x, short* __restrict__ xb,
    const float* __restrict__ Wq, const float* __restrict__ Wk,
    const float* __restrict__ Wv, short* __restrict__ Wt) {
  __shared__ float T[64][65];
  if (blockIdx.x < 4096) {
    int i = (blockIdx.x * 256 + threadIdx.x) * 8;
    f32x4 a = *(const f32x4*)(x + i);
    f32x4 b = *(const f32x4*)(x + i + 4);
    s16x8 h;
    h[0] = (short)f2bf(a[0]); h[1] = (short)f2bf(a[1]);
    h[2] = (short)f2bf(a[2]); h[3] = (short)f2bf(a[3]);
    h[4] = (short)f2bf(b[0]); h[5] = (short)f2bf(b[1]);
    h[6] = (short)f2bf(b[2]); h[7] = (short)f2bf(b[3]);
    *(s16x8*)(xb + i) = h;
  } else {
    int bid = blockIdx.x - 4096;
    int mat = bid >> 6;
    int t   = bid & 63;
    int k0  = (t & 7) << 6, n0 = (t >> 3) << 6;
    const float* W = (mat == 0) ? Wq : (mat == 1) ? Wk : Wv;
    int tid = threadIdx.x;
    int rr = tid >> 4, cc = tid & 15;
#pragma unroll
    for (int p = 0; p < 4; ++p) {
      int row = p * 16 + rr;
      f32x4 v = *(const f32x4*)(W + (size_t)(k0 + row) * 512 + n0 + cc * 4);
#pragma unroll
      for (int j = 0; j < 4; ++j) T[row][cc * 4 + j] = v[j];
    }
    __syncthreads();
    short* D = Wt + (size_t)mat * 262144;
#pragma unroll
    for (int p = 0; p < 4; ++p) {
      int nrow = p * 16 + rr;
      u16x4 h;
#pragma unroll
      for (int j = 0; j < 4; ++j) h[j] = f2bf(T[cc * 4 + j][nrow]);
      *(u16x4*)(D + (size_t)(n0 + nrow) * 512 + k0 + cc * 4) = h;
    }
  }
}

// ---------------- kernel 1: QKV projection GEMM (pipelined + XCD-pinned + LDS epilogue) ----------------
__global__ __launch_bounds__(256) void qkv_gemm(
    const short* __restrict__ xb, const short* __restrict__ Wt,
    const float* __restrict__ bq, const float* __restrict__ bk,
    const float* __restrict__ bv,
    short* __restrict__ Qg, short* __restrict__ Kg, short* __restrict__ VTg) {
  __shared__ __align__(16) short As[2][128 * 64];
  __shared__ __align__(16) short Bs[2][128 * 64];
  int gid = blockIdx.x;
  int xcd = gid & 7;
  int s   = gid >> 3;
  int mt_l = s / 12;
  int j    = s - mt_l * 12;
  int mat  = j >> 2;
  int nt   = j & 3;
  int mt   = xcd * 16 + mt_l;
  int m0   = mt << 7, n0 = nt << 7;
  const short* W    = Wt + (size_t)mat * 262144;
  const float* bias = (mat == 0) ? bq : (mat == 1) ? bk : bv;

  int tid = threadIdx.x, lane = tid & 63, wv = tid >> 6;
  int l16 = lane & 15, quad = lane >> 4;
  int wr = (wv & 1) << 6, wc = (wv >> 1) << 6;
  int drow = lane >> 3;
  int dchk = (lane & 7) ^ drow;

  const short* asrc[4];
  const short* bsrc[4];
#pragma unroll
  for (int i = 0; i < 4; ++i) {
    int row = (wv * 4 + i) * 8 + drow;
    asrc[i] = xb + (size_t)(m0 + row) * 512 + dchk * 8;
    bsrc[i] = W  + (size_t)(n0 + row) * 512 + dchk * 8;
  }

  const f32x4 Z4 = {0.f, 0.f, 0.f, 0.f};
  f32x4 acc[4][4];
#pragma unroll
  for (int a = 0; a < 4; ++a)
#pragma unroll
    for (int c = 0; c < 4; ++c) acc[a][c] = Z4;

#pragma unroll
  for (int i = 0; i < 4; ++i) {
    int g = wv * 4 + i;
    ASYNC16(asrc[i], &As[0][g * 512]);
    ASYNC16(bsrc[i], &Bs[0][g * 512]);
  }
  __syncthreads();

  for (int it = 0; it < 8; ++it) {
    int buf = it & 1;
    if (it < 7) {
      int k1 = (it + 1) << 6;
#pragma unroll
      for (int i = 0; i < 4; ++i) {
        int g = wv * 4 + i;
        ASYNC16(asrc[i] + k1, &As[buf ^ 1][g * 512]);
        ASYNC16(bsrc[i] + k1, &Bs[buf ^ 1][g * 512]);
      }
    }
#pragma unroll
    for (int kk = 0; kk < 2; ++kk) {
      s16x8 af[4], bfr[4];
#pragma unroll
      for (int rb = 0; rb < 4; ++rb) {
        int row = wr + rb * 16 + l16;
        int c   = kk * 4 + quad;
        af[rb] = *(const s16x8*)(&As[buf][row * 64 + ((c ^ (row & 7)) * 8)]);
      }
#pragma unroll
      for (int cb = 0; cb < 4; ++cb) {
        int row = wc + cb * 16 + l16;
        int c   = kk * 4 + quad;
        bfr[cb] = *(const s16x8*)(&Bs[buf][row * 64 + ((c ^ (row & 7)) * 8)]);
      }
#pragma unroll
      for (int rb = 0; rb < 4; ++rb)
#pragma unroll
        for (int cb = 0; cb < 4; ++cb)
          acc[rb][cb] = __builtin_amdgcn_mfma_f32_16x16x32_bf16(af[rb], bfr[cb], acc[rb][cb], 0, 0, 0);
    }
    __syncthreads();   // final iter's barrier also fences As reads before Ct reuse
  }

  float bsv[4];
#pragma unroll
  for (int cb = 0; cb < 4; ++cb) bsv[cb] = bias[n0 + wc + cb * 16 + l16];

  if (mat < 2) {
    // LDS-transposed epilogue: acc -> swizzled 128x128 bf16 tile in dead As,
    // then coalesced s16x8 stores (256B full-line segments).
    short* D  = (mat == 0) ? Qg : Kg;
    short* Ct = &As[0][0];   // 32 KB, exactly 128x128 bf16
#pragma unroll
    for (int rb = 0; rb < 4; ++rb)
#pragma unroll
      for (int cb = 0; cb < 4; ++cb)
#pragma unroll
        for (int r = 0; r < 4; ++r) {
          int m_l = wr + rb * 16 + quad * 4 + r;
          int e_l = wc + cb * 16 + l16;
          int cc  = e_l >> 3;
          Ct[m_l * 128 + ((cc ^ (m_l & 7)) * 8) + (e_l & 7)] =
              (short)f2bf(acc[rb][cb][r] + bsv[cb]);
        }
    __syncthreads();
#pragma unroll
    for (int g = 0; g < 8; ++g) {
      int row = wv * 32 + g * 4 + (lane >> 4);
      int cc  = lane & 15;
      s16x8 v = *(const s16x8*)(Ct + row * 128 + ((cc ^ (row & 7)) * 8));
      *(s16x8*)(D + (size_t)(m0 + row) * 512 + n0 + cc * 8) = v;
    }
  } else {
    // V: tiled transpose layout [bb][e>>4][s>>5][e&15][s&31], 1KB tiles
#pragma unroll
    for (int rb = 0; rb < 4; ++rb)
#pragma unroll
      for (int cb = 0; cb < 4; ++cb) {
        u16x4 h;
#pragma unroll
        for (int r = 0; r < 4; ++r) h[r] = f2bf(acc[rb][cb][r] + bsv[cb]);
        int m  = m0 + wr + rb * 16 + quad * 4;
        int bb = m >> 11, sl = m & 2047;
        int e  = n0 + wc + cb * 16 + l16;
        size_t idx = ((((size_t)bb * 32 + (e >> 4)) * 64 + (sl >> 5)) * 16 +
                      (e & 15)) * 32 + (sl & 31);
        *(u16x4*)(VTg + idx) = h;
      }
  }
}

// ---------------- kernel 2: flash attention v9 (producer/consumer + rotation) ----------------
__global__ __launch_bounds__(512, 2) void attn_kernel(
    const short* __restrict__ Qg, const short* __restrict__ Kg,
    const short* __restrict__ VTg, float* __restrict__ out) {
  __shared__ __align__(16) short Kt[3][32 * 512];   // 96 KB triple buffer
  __shared__ __align__(16) short Pl[2][64 * 40];    // 10 KB double buffer
  __shared__ float l_l[64];
  const float SCL2 = 0.06375871855f;  // log2(e)/sqrt(512)

  int b = blockIdx.x & 7, qt = blockIdx.x >> 3;   // qt 0..31
  int s0 = qt << 6;                                // 64 rows/block
  int rot = (qt << 1) & 63;                        // per-block tile phase
  int tid = threadIdx.x, lane = tid & 63, wv = tid >> 6;  // wv 0..7
  int l16 = lane & 15, quad = lane >> 4;

  const short* Kb = Kg  + (size_t)b * S_LEN * 512;
  const short* Vb = VTg + (size_t)b * 1048576;     // [32 et][64 st][16][32]

  const short* kdma[4];
#pragma unroll
  for (int i = 0; i < 4; ++i) {
    int r = wv * 4 + i;
    kdma[i] = Kb + (size_t)r * 512 + ((lane ^ (r & 7)) * 8);
  }

  {
    size_t a0 = (size_t)rot * 16384;
    size_t a1 = (size_t)((rot + 1) & 63) * 16384;
#pragma unroll
    for (int i = 0; i < 4; ++i)
      ASYNC16(kdma[i] + a0, &Kt[0][(wv * 4 + i) * 512]);
#pragma unroll
    for (int i = 0; i < 4; ++i)
      ASYNC16(kdma[i] + a1, &Kt[1][(wv * 4 + i) * 512]);
  }

  if (wv < 4) {
    // ================= QK producer branch =================
    int a = wv & 1, h = wv >> 1;
    const short* qrowA = Qg + ((size_t)b * S_LEN + s0 + a * 32 + l16) * 512 + quad * 8;
    const short* qrowB = qrowA + (size_t)16 * 512;
    s16x8 qfA[16], qfB[16];
#pragma unroll
    for (int c = 0; c < 16; ++c) {
      qfA[c] = *(const s16x8*)(qrowA + c * 32);
      qfB[c] = *(const s16x8*)(qrowB + c * 32);
    }
    const f32x4 Z4 = {0.f, 0.f, 0.f, 0.f};
    f32x4 lsumA = Z4, lsumB = Z4;

    __syncthreads();   // prologue drain  [barrier #0]

    for (int kt = 0; kt < 64; ++kt) {
      int rbuf = kt % 3, wbuf = (kt + 2) % 3;
      {
        size_t adv = (size_t)((kt + 2 + rot) & 63) * 16384;
#pragma unroll
        for (int i = 0; i < 4; ++i)
          ASYNC16(kdma[i] + adv, &Kt[wbuf][(wv * 4 + i) * 512]);
      }
      __builtin_amdgcn_sched_barrier(0);

      f32x4 sA = Z4, sB = Z4;
      int krow = h * 16 + l16;
      const short* kb = &Kt[rbuf][krow * 512];
      int ksw = krow & 7;
      __builtin_amdgcn_s_setprio(1);
#pragma unroll
      for (int c = 0; c < 16; ++c) {
        s16x8 kf = *(const s16x8*)(kb + (((c * 4 + quad) ^ ksw) * 8));
        sA = __builtin_amdgcn_mfma_f32_16x16x32_bf16(qfA[c], kf, sA, 0, 0, 0);
        sB = __builtin_amdgcn_mfma_f32_16x16x32_bf16(qfB[c], kf, sB, 0, 0, 0);
      }
      __builtin_amdgcn_s_setprio(0);

      short* Pc = Pl[kt & 1];
#pragma unroll
      for (int r = 0; r < 4; ++r) {
        float pA = exp2f(sA[r] * SCL2);
        lsumA[r] += pA;
        Pc[(a * 32 + quad * 4 + r) * 40 + h * 16 + l16] = (short)f2bf(pA);
        float pB = exp2f(sB[r] * SCL2);
        lsumB[r] += pB;
        Pc[(a * 32 + 16 + quad * 4 + r) * 40 + h * 16 + l16] = (short)f2bf(pB);
      }

      asm volatile("s_waitcnt vmcnt(4) lgkmcnt(0)\n\ts_barrier" ::: "memory");
      __builtin_amdgcn_sched_barrier(0);
    }

#pragma unroll
    for (int r = 0; r < 4; ++r) {
      float vA = lsumA[r];
      vA += __shfl_xor(vA, 1); vA += __shfl_xor(vA, 2);
      vA += __shfl_xor(vA, 4); vA += __shfl_xor(vA, 8);
      lsumA[r] = vA;
      float vB = lsumB[r];
      vB += __shfl_xor(vB, 1); vB += __shfl_xor(vB, 2);
      vB += __shfl_xor(vB, 4); vB += __shfl_xor(vB, 8);
      lsumB[r] = vB;
    }
    if (h == 0 && l16 == 0) {
#pragma unroll
      for (int r = 0; r < 4; ++r) {
        l_l[a * 32 + quad * 4 + r]      = lsumA[r];
        l_l[a * 32 + 16 + quad * 4 + r] = lsumB[r];
      }
    }
    __syncthreads();   // epilogue barrier #1
    if (h == 1 && l16 == 0) {
#pragma unroll
      for (int r = 0; r < 4; ++r) {
        l_l[a * 32 + quad * 4 + r]      += lsumA[r];
        l_l[a * 32 + 16 + quad * 4 + r] += lsumB[r];
      }
    }
    __syncthreads();   // epilogue barrier #2
  } else {
    // ================= PV consumer branch =================
    int pw = wv - 4;
    int e0 = pw << 7;
    const short* vbase = Vb + (size_t)pw * 262144 + l16 * 32 + quad * 8;

    const f32x4 Z4 = {0.f, 0.f, 0.f, 0.f};
    f32x4 acc[4][8];
#pragma unroll
    for (int g = 0; g < 4; ++g)
#pragma unroll
      for (int cb = 0; cb < 8; ++cb) acc[g][cb] = Z4;
    s16x8 vfA[8], vfB[8];

    __syncthreads();   // prologue drain  [barrier #0]

    for (int kt = 0; kt < 64; kt += 2) {
      {
        size_t adv = (size_t)((kt + 2 + rot) & 63) * 16384;
        int wbuf = (kt + 2) % 3;
#pragma unroll
        for (int i = 0; i < 4; ++i)
          ASYNC16(kdma[i] + adv, &Kt[wbuf][(wv * 4 + i) * 512]);
      }
      {
        size_t vadv = (size_t)((kt + rot) & 63) * 512;
#pragma unroll
        for (int cb = 0; cb < 8; ++cb)
          vfA[cb] = *(const s16x8*)(vbase + (size_t)cb * 32768 + vadv);
      }
      if (kt) {
        s16x8 pf[4];
#pragma unroll
        for (int g = 0; g < 4; ++g)
          pf[g] = *(const s16x8*)(&Pl[1][(g * 16 + l16) * 40 + quad * 8]);
        __builtin_amdgcn_s_setprio(1);
#pragma unroll
        for (int cb = 0; cb < 8; ++cb)
#pragma unroll
          for (int g = 0; g < 4; ++g)
            acc[g][cb] = __builtin_amdgcn_mfma_f32_16x16x32_bf16(pf[g], vfB[cb], acc[g][cb], 0, 0, 0);
        __builtin_amdgcn_s_setprio(0);
      }
      asm volatile("s_waitcnt lgkmcnt(0)\n\ts_barrier" ::: "memory");
      __builtin_amdgcn_sched_barrier(0);

      {
        size_t adv = (size_t)((kt + 3 + rot) & 63) * 16384;
        int wbuf = (kt + 3) % 3;
#pragma unroll
        for (int i = 0; i < 4; ++i)
          ASYNC16(kdma[i] + adv, &Kt[wbuf][(wv * 4 + i) * 512]);
      }
      {
        size_t vadv = (size_t)((kt + 1 + rot) & 63) * 512;
#pragma unroll
        for (int cb = 0; cb < 8; ++cb)
          vfB[cb] = *(const s16x8*)(vbase + (size_t)cb * 32768 + vadv);
      }
      {
        s16x8 pf[4];
#pragma unroll
        for (int g = 0; g < 4; ++g)
          pf[g] = *(const s16x8*)(&Pl[0][(g * 16 + l16) * 40 + quad * 8]);
        __builtin_amdgcn_s_setprio(1);
#pragma unroll
        for (int cb = 0; cb < 8; ++cb)
#pragma unroll
          for (int g = 0; g < 4; ++g)
            acc[g][cb] = __builtin_amdgcn_mfma_f32_16x16x32_bf16(pf[g], vfA[cb], acc[g][cb], 0, 0, 0);
        __builtin_amdgcn_s_setprio(0);
      }
      asm volatile("s_waitcnt lgkmcnt(0)\n\ts_barrier" ::: "memory");
      __builtin_amdgcn_sched_barrier(0);
    }

    asm volatile("s_waitcnt vmcnt(0)" ::: "memory");
    __builtin_amdgcn_sched_barrier(0);
    {
      s16x8 pf[4];
#pragma unroll
      for (int g = 0; g < 4; ++g)
        pf[g] = *(const s16x8*)(&Pl[1][(g * 16 + l16) * 40 + quad * 8]);
#pragma unroll
      for (int cb = 0; cb < 8; ++cb)
#pragma unroll
        for (int g = 0; g < 4; ++g)
          acc[g][cb] = __builtin_amdgcn_mfma_f32_16x16x32_bf16(pf[g], vfB[cb], acc[g][cb], 0, 0, 0);
    }
    __syncthreads();   // epilogue barrier #1
    __syncthreads();   // epilogue barrier #2

#pragma unroll
    for (int g = 0; g < 4; ++g) {
      f32x4 lv = *(const f32x4*)(l_l + g * 16 + quad * 4);
      f32x4 li;
#pragma unroll
      for (int r = 0; r < 4; ++r) li[r] = 1.0f / lv[r];
#pragma unroll
      for (int cb = 0; cb < 8; ++cb)
#pragma unroll
        for (int r = 0; r < 4; ++r)
          out[((size_t)b * S_LEN + s0 + g * 16 + quad * 4 + r) * 512 + e0 + cb * 16 + l16] =
              acc[g][cb][r] * li[r];
    }
  }
}

// ---------------- host launch ----------------
extern "C" void kernel_launch(void* const* d_in, const int* in_sizes, int n_in,
                              void* d_out, int out_size, void* d_ws, size_t ws_size,
                              hipStream_t stream) {
  const float* x  = (const float*)d_in[0];
  const float* Wq = (const float*)d_in[1];
  const float* bq = (const float*)d_in[2];
  const float* Wk = (const float*)d_in[3];
  const float* bk = (const float*)d_in[4];
  const float* Wv = (const float*)d_in[5];
  const float* bv = (const float*)d_in[6];

  short* Wt  = (short*)d_ws;
  short* xb  = (short*)((char*)d_ws + 1572864);
  short* Qg  = xb + (size_t)8388608;
  short* Kg  = Qg + (size_t)8388608;
  short* VTg = Kg + (size_t)8388608;

  conv_kernel<<<4288, 256, 0, stream>>>(x, xb, Wq, Wk, Wv, Wt);
  qkv_gemm<<<1536, 256, 0, stream>>>(xb, Wt, bq, bk, bv, Qg, Kg, VTg);
  attn_kernel<<<256, 512, 0, stream>>>(Qg, Kg, VTg, (float*)d_out);
}